// Round 6
// baseline (246.862 us; speedup 1.0000x reference)
//
#include <hip/hip_runtime.h>

#define NBATCH 8
#define TW 64          // tile width  (output)
#define TH 32          // tile height (output)
#define SROWS 42       // staged rows: image rows -5..36  (TH + 10)
#define SQUADS 20      // staged quads/row: image cols -8..71 (80 floats)
#define STRDQ 84       // LDS row stride in floats (21 quads; row-pair stride = 8 banks)
#define NSTRIP 180     // 20 row-pairs x 9 col-octs (region rows -4..35, cols -4..67)
#define NTHR 192

// accumulate one stencil row: window floats [L, m.x..m.w, R], weights ka,kb,kc
__device__ __forceinline__ void acc_row(float4& v, float L, float4 m, float R,
                                        float ka, float kb, float kc) {
    v.x += ka * L   + kb * m.x + kc * m.y;
    v.y += ka * m.x + kb * m.y + kc * m.z;
    v.z += ka * m.y + kb * m.z + kc * m.w;
    v.w += ka * m.z + kb * m.w + kc * R;
}

// ---------------------------------------------------------------------------
// 5 fused conv3x3+bias+BU+clamp iterations; all 3 pyramid levels, one dispatch.
// One 64x32 output tile per 192-thread block. SINGLE LDS buffer 42x84 =
// 14.1 KB, updated IN PLACE: each iteration is {read window to regs; barrier;
// compute+write back; barrier}. All reads complete before any write, so the
// ping-pong buffer is unnecessary -> LDS no longer caps occupancy.
// Thread t (<180) owns one 8x2-px strip: 16 aligned ds_read_b128 + 4 aligned
// ds_write_b128 per iteration. Validity erodes 1 ring/iter from the staged
// rows -5..36 / cols -5..71 rim (unwritten rim cells go stale = invalid, same
// erosion schedule as ping-pong): valid(t) rows/cols [-4+t-1.. ] => after 5
// iters the 64x32 interior is exact. Out-of-image cells re-masked to 0 every
// iter (true zero-pad semantics); clamp sanitizes garbage/NaN to finite.
// ---------------------------------------------------------------------------
__global__ __launch_bounds__(NTHR) void conv5_all(
    const float* __restrict__ srcU, const float* __restrict__ buU,
    const float* __restrict__ wtU, const float* __restrict__ bsU,
    const float* __restrict__ srcX, const float* __restrict__ buX,
    const float* __restrict__ wtX, const float* __restrict__ bsX,
    const float* __restrict__ srcD, const float* __restrict__ buD,
    const float* __restrict__ wtD, const float* __restrict__ bsD,
    float* __restrict__ dstU, float* __restrict__ dstX, float* __restrict__ dstD)
{
    __shared__ __align__(16) float buf[SROWS * STRDQ];

    const int tid = threadIdx.x;
    const int blk = blockIdx.x;

    const float* src; const float* BU; const float* wt; const float* bs;
    float* dst; int HW; int tx, ty, b;
    if (blk < 4096) {                 // up: 8 x (32 ty x 16 tx)
        src = srcU; BU = buU; wt = wtU; bs = bsU; dst = dstU; HW = 1024;
        b = blk >> 9; int rem = blk & 511; ty = rem >> 4; tx = rem & 15;
    } else if (blk < 5120) {          // x: 8 x (16 ty x 8 tx)
        int t = blk - 4096;
        src = srcX; BU = buX; wt = wtX; bs = bsX; dst = dstX; HW = 512;
        b = t >> 7; int rem = t & 127; ty = rem >> 3; tx = rem & 7;
    } else {                          // down: 8 x (8 ty x 4 tx)
        int t = blk - 5120;
        src = srcD; BU = buD; wt = wtD; bs = bsD; dst = dstD; HW = 256;
        b = t >> 5; int rem = t & 31; ty = rem >> 2; tx = rem & 3;
    }
    const int bh0 = ty * TH, bw0 = tx * TW;
    const long base = (long)b * HW * HW;

    // ---- stage: image rows -5..36, cols -8..71 -> buf (img col c -> buf col c+8)
    for (int q = tid; q < SROWS * SQUADS; q += NTHR) {
        int r = q / SQUADS, cq = q - r * SQUADS;
        int gh = bh0 + r - 5;
        int gw = bw0 + (cq << 2) - 8;
        float4 v = {0.0f, 0.0f, 0.0f, 0.0f};
        if ((unsigned)gh < (unsigned)HW) {
            const float* gp = src + base + (long)gh * HW + gw;
            if (gw >= 0 && gw + 3 < HW) {
                v = *(const float4*)gp;
            } else {
                if ((unsigned)(gw + 0) < (unsigned)HW) v.x = gp[0];
                if ((unsigned)(gw + 1) < (unsigned)HW) v.y = gp[1];
                if ((unsigned)(gw + 2) < (unsigned)HW) v.z = gp[2];
                if ((unsigned)(gw + 3) < (unsigned)HW) v.w = gp[3];
            }
        }
        *(float4*)&buf[r * STRDQ + (cq << 2)] = v;
    }

    const float k00 = wt[0], k01 = wt[1], k02 = wt[2];
    const float k10 = wt[3], k11 = wt[4], k12 = wt[5];
    const float k20 = wt[6], k21 = wt[7], k22 = wt[8];
    const float bias = bs[0];

    // ---- per-thread strip setup (strip s=tid: rp=s/9 row-pair, j=s%9 col-oct)
    // outputs: image rows 2rp-4+i (i=0,1), cols 8j-4+k (k=0..7)
    // window quads: buffer rows 2rp..2rp+3, quads at 8j, 8j+4, 8j+8, 8j+12
    const bool act = (tid < NSTRIP);
    int sc = act ? tid : 0;
    int rp = sc / 9, j = sc - rp * 9;
    const int qbase = (2 * rp) * STRDQ + 8 * j;

    float4 wf0, wf1;                  // column in-image masks (k=0..3, 4..7)
    {
        float* p0 = (float*)&wf0; float* p1 = (float*)&wf1;
        #pragma unroll
        for (int k = 0; k < 4; ++k) {
            p0[k] = ((unsigned)(bw0 + 8 * j - 4 + k) < (unsigned)HW) ? 1.0f : 0.0f;
            p1[k] = ((unsigned)(bw0 + 8 * j + k)     < (unsigned)HW) ? 1.0f : 0.0f;
        }
    }
    float hf[2];
    float4 bu0[2], bu1[2];            // (BU + bias), pre-masked 0 outside image
    #pragma unroll
    for (int i = 0; i < 2; ++i) {
        int gh = bh0 + 2 * rp - 4 + i;
        bool hok = act && ((unsigned)gh < (unsigned)HW);
        hf[i] = hok ? 1.0f : 0.0f;
        float* b0 = (float*)&bu0[i]; float* b1 = (float*)&bu1[i];
        #pragma unroll
        for (int k = 0; k < 4; ++k) {
            int gw0 = bw0 + 8 * j - 4 + k;
            int gw1 = bw0 + 8 * j + k;
            b0[k] = (hok && (unsigned)gw0 < (unsigned)HW)
                        ? (BU[base + (long)gh * HW + gw0] + bias) : 0.0f;
            b1[k] = (hok && (unsigned)gw1 < (unsigned)HW)
                        ? (BU[base + (long)gh * HW + gw1] + bias) : 0.0f;
        }
    }

    for (int it = 0; it < 5; ++it) {
        __syncthreads();              // staging done / previous writes done
        float4 q[4][4];
        if (act) {
            const float* bp = buf + qbase;
            #pragma unroll
            for (int r = 0; r < 4; ++r) {
                q[r][0] = *(const float4*)(bp + r * STRDQ);
                q[r][1] = *(const float4*)(bp + r * STRDQ + 4);
                q[r][2] = *(const float4*)(bp + r * STRDQ + 8);
                q[r][3] = *(const float4*)(bp + r * STRDQ + 12);
            }
        }
        __syncthreads();              // all reads done before any write
        if (act) {
            float* wp = buf + qbase;
            #pragma unroll
            for (int i = 0; i < 2; ++i) {
                float4 v0 = bu0[i];
                float4 v1 = bu1[i];
                acc_row(v0, q[i][0].w,     q[i][1],     q[i][2].x,     k00, k01, k02);
                acc_row(v0, q[i + 1][0].w, q[i + 1][1], q[i + 1][2].x, k10, k11, k12);
                acc_row(v0, q[i + 2][0].w, q[i + 2][1], q[i + 2][2].x, k20, k21, k22);
                acc_row(v1, q[i][1].w,     q[i][2],     q[i][3].x,     k00, k01, k02);
                acc_row(v1, q[i + 1][1].w, q[i + 1][2], q[i + 1][3].x, k10, k11, k12);
                acc_row(v1, q[i + 2][1].w, q[i + 2][2], q[i + 2][3].x, k20, k21, k22);
                float m = hf[i];
                v0.x = fminf(1.0f, fmaxf(-1.0f, v0.x)) * (m * wf0.x);
                v0.y = fminf(1.0f, fmaxf(-1.0f, v0.y)) * (m * wf0.y);
                v0.z = fminf(1.0f, fmaxf(-1.0f, v0.z)) * (m * wf0.z);
                v0.w = fminf(1.0f, fmaxf(-1.0f, v0.w)) * (m * wf0.w);
                v1.x = fminf(1.0f, fmaxf(-1.0f, v1.x)) * (m * wf1.x);
                v1.y = fminf(1.0f, fmaxf(-1.0f, v1.y)) * (m * wf1.y);
                v1.z = fminf(1.0f, fmaxf(-1.0f, v1.z)) * (m * wf1.z);
                v1.w = fminf(1.0f, fmaxf(-1.0f, v1.w)) * (m * wf1.w);
                *(float4*)(wp + (i + 1) * STRDQ + 4) = v0;
                *(float4*)(wp + (i + 1) * STRDQ + 8) = v1;
            }
        }
    }
    __syncthreads();

    // ---- store 64x32 interior: image (r,c) -> buffer (r+5, c+8), quad-aligned
    for (int i2 = tid; i2 < TH * (TW / 4); i2 += NTHR) {
        int r = i2 >> 4;
        int cq = i2 & 15;
        float4 v = *(const float4*)&buf[(r + 5) * STRDQ + 8 + (cq << 2)];
        *(float4*)&dst[base + (long)(bh0 + r) * HW + bw0 + (cq << 2)] = v;
    }
}

// ---------------------------------------------------------------------------
// Cross-scale 1x1-conv fusion: one thread per down-level pixel; U/X/D read
// exactly once, all three outputs written.
// ---------------------------------------------------------------------------
__global__ __launch_bounds__(256) void fuse_all(
    const float* __restrict__ X,   // 8 x 512^2
    const float* __restrict__ D,   // 8 x 256^2
    const float* __restrict__ U,   // 8 x 1024^2
    const float* __restrict__ cx,
    const float* __restrict__ cd,
    const float* __restrict__ cu,
    float* __restrict__ xo, float* __restrict__ dno, float* __restrict__ upo)
{
    const int total = NBATCH << 16;  // 8*256*256
    int idx = blockIdx.x * blockDim.x + threadIdx.x;
    if (idx >= total) return;
    int wd = idx & 255;
    int hd = (idx >> 8) & 255;
    int b  = idx >> 16;

    const float cx0 = cx[0], cx1 = cx[1], cx2 = cx[2];
    const float cd0 = cd[0], cd1 = cd[1], cd2 = cd[2];
    const float cu0 = cu[0], cu1 = cu[1], cu2 = cu[2];

    int ub = (b << 20) + ((hd << 2) << 10) + (wd << 2);
    float4 u0 = *(const float4*)&U[ub];
    float4 u1 = *(const float4*)&U[ub + 1024];
    float4 u2 = *(const float4*)&U[ub + 2048];
    float4 u3 = *(const float4*)&U[ub + 3072];
    int xb = (b << 18) + ((hd << 1) << 9) + (wd << 1);
    float2 x0 = *(const float2*)&X[xb];
    float2 x1 = *(const float2*)&X[xb + 512];
    float dv = D[idx];

    float p00 = 0.25f * (u0.x + u0.y + u1.x + u1.y);
    float p01 = 0.25f * (u0.z + u0.w + u1.z + u1.w);
    float p10 = 0.25f * (u2.x + u2.y + u3.x + u3.y);
    float p11 = 0.25f * (u2.z + u2.w + u3.z + u3.w);
    float pu4 = 0.25f * (p00 + p01 + p10 + p11);
    float px2 = 0.25f * (x0.x + x0.y + x1.x + x1.y);

    dno[idx] = cd0 * pu4 + cd1 * px2 + cd2 * dv;

    float2 xo0, xo1;
    xo0.x = cx0 * p00 + cx1 * x0.x + cx2 * dv;
    xo0.y = cx0 * p01 + cx1 * x0.y + cx2 * dv;
    xo1.x = cx0 * p10 + cx1 * x1.x + cx2 * dv;
    xo1.y = cx0 * p11 + cx1 * x1.y + cx2 * dv;
    *(float2*)&xo[xb]       = xo0;
    *(float2*)&xo[xb + 512] = xo1;

    float4 o0, o1, o2, o3;
    o0.x = cu0 * u0.x + cu1 * x0.x + cu2 * dv;
    o0.y = cu0 * u0.y + cu1 * x0.x + cu2 * dv;
    o0.z = cu0 * u0.z + cu1 * x0.y + cu2 * dv;
    o0.w = cu0 * u0.w + cu1 * x0.y + cu2 * dv;
    o1.x = cu0 * u1.x + cu1 * x0.x + cu2 * dv;
    o1.y = cu0 * u1.y + cu1 * x0.x + cu2 * dv;
    o1.z = cu0 * u1.z + cu1 * x0.y + cu2 * dv;
    o1.w = cu0 * u1.w + cu1 * x0.y + cu2 * dv;
    o2.x = cu0 * u2.x + cu1 * x1.x + cu2 * dv;
    o2.y = cu0 * u2.y + cu1 * x1.x + cu2 * dv;
    o2.z = cu0 * u2.z + cu1 * x1.y + cu2 * dv;
    o2.w = cu0 * u2.w + cu1 * x1.y + cu2 * dv;
    o3.x = cu0 * u3.x + cu1 * x1.x + cu2 * dv;
    o3.y = cu0 * u3.y + cu1 * x1.x + cu2 * dv;
    o3.z = cu0 * u3.z + cu1 * x1.y + cu2 * dv;
    o3.w = cu0 * u3.w + cu1 * x1.y + cu2 * dv;
    *(float4*)&upo[ub]        = o0;
    *(float4*)&upo[ub + 1024] = o1;
    *(float4*)&upo[ub + 2048] = o2;
    *(float4*)&upo[ub + 3072] = o3;
}

// ---------------------------------------------------------------------------
extern "C" void kernel_launch(void* const* d_in, const int* in_sizes, int n_in,
                              void* d_out, int out_size, void* d_ws, size_t ws_size,
                              hipStream_t stream)
{
    const float* x    = (const float*)d_in[0];
    const float* down = (const float*)d_in[1];
    const float* up   = (const float*)d_in[2];
    const float* BUx  = (const float*)d_in[3];
    const float* BUd  = (const float*)d_in[4];
    const float* BUu  = (const float*)d_in[5];
    const float* wAx  = (const float*)d_in[6];
    const float* bx   = (const float*)d_in[7];
    const float* wAd  = (const float*)d_in[8];
    const float* bd   = (const float*)d_in[9];
    const float* wAu  = (const float*)d_in[10];
    const float* bu   = (const float*)d_in[11];
    const float* c1x  = (const float*)d_in[12];
    const float* c1d  = (const float*)d_in[13];
    const float* c1u  = (const float*)d_in[14];

    float* out = (float*)d_out;
    float* ws  = (float*)d_ws;

    const int NX = NBATCH * 512 * 512;
    const int ND = NBATCH * 256 * 256;

    float* wsX = ws;
    float* wsD = ws + NX;
    float* wsU = ws + NX + ND;
    float* outX = out;
    float* outD = out + NX;
    float* outU = out + NX + ND;

    // one dispatch, all levels: 4096 up + 1024 x + 256 down tiles (64x32 each)
    conv5_all<<<5376, NTHR, 0, stream>>>(
        up,   BUu, wAu, bu,
        x,    BUx, wAx, bx,
        down, BUd, wAd, bd,
        wsU, wsX, wsD);

    fuse_all<<<(ND + 255) / 256, 256, 0, stream>>>(wsX, wsD, wsU, c1x, c1d, c1u,
                                                   outX, outD, outU);
}